// Round 19
// baseline (383.975 us; speedup 1.0000x reference)
//
#include <hip/hip_runtime.h>

typedef __bf16 bf16x8 __attribute__((ext_vector_type(8)));
typedef unsigned short u16x8 __attribute__((ext_vector_type(8)));
typedef unsigned short u16x4 __attribute__((ext_vector_type(4)));
typedef float f32x4 __attribute__((ext_vector_type(4)));

#define DEV static __device__ __forceinline__

DEV unsigned short f2bf(float f) {
  union { float f; unsigned u; } v; v.f = f;
  unsigned u = v.u + 0x7FFFu + ((v.u >> 16) & 1u);
  return (unsigned short)(u >> 16);
}

// HW bf16 convert (v_cvt, RNE) - 1 VALU op vs 4 for the manual version.
DEV unsigned short f2bf_hw(float f) {
  union { __bf16 b; unsigned short u; } v;
  v.b = (__bf16)f;
  return v.u;
}

DEV float bf2f(unsigned short b) {
  union { unsigned u; float f; } v; v.u = ((unsigned)b) << 16;
  return v.f;
}

DEV float fast_exp2(float x) { return __builtin_amdgcn_exp2f(x); }

// XOR swizzle within a [row][64] bf16 tile: element offset.
DEV int swz(int row, int k) { return row * 64 + (k ^ ((row & 7) * 8)); }

// V-tile swizzle: extra (row>>3) XOR term for the register-staged V transpose
// (verified: SQ_LDS_BANK_CONFLICT 5.87e7 -> 8.4e6, R10->R12).
DEV int swzV(int row, int k) {
  return row * 64 + (k ^ ((row & 7) * 8) ^ (((row >> 3) & 7) * 8));
}

#define GLOAD16(gp, lp)                                                        \
  __builtin_amdgcn_global_load_lds(                                            \
      (const __attribute__((address_space(1))) void*)(const void*)(gp),        \
      (__attribute__((address_space(3))) void*)(void*)(lp), 16, 0, 0)

// ---------------- kernel 0: detect mask dtype (R3-proven) ----------------
__global__ __launch_bounds__(256) void k_detect(const unsigned* m, int* flag) {
  __shared__ int sF, sI;
  if (threadIdx.x == 0) { sF = 1; sI = 1; }
  __syncthreads();
  int lF = 1, lI = 1;
  for (int i = threadIdx.x; i < 4096; i += 256) {
    unsigned d = m[i];
    lF &= (d == 0u || d == 0x3F800000u);
    lI &= (d == 0u || d == 1u);
  }
  if (!lF) atomicAnd(&sF, 0);
  if (!lI) atomicAnd(&sI, 0);
  __syncthreads();
  if (threadIdx.x == 0) flag[0] = sF ? 2 : (sI ? 0 : 1);
}

// ---------------- kernel 1: pack mask to bitmask (R3-proven) ----------------
__global__ __launch_bounds__(256) void k_pack(const void* m, const int* flag,
                                              unsigned long long* bits) {
  const int tid = threadIdx.x;
  const int w = blockIdx.x * 4 + (tid >> 6);
  const int lane = tid & 63;
  const size_t idx = (size_t)w * 64 + lane;
  const int fl = flag[0];
  int v;
  if (fl == 1)      v = ((const unsigned char*)m)[idx];
  else if (fl == 0) v = ((const int*)m)[idx];
  else              v = (((const float*)m)[idx] != 0.f);
  unsigned long long bal = __ballot(v != 0);
  if (lane == 0) bits[w] = bal;
}

// ---------------- kernel 2: fp32 -> bf16 (R3-proven) ----------------
__global__ __launch_bounds__(256) void k_cvt(const float* a, const float* b,
                                             const float* c, unsigned short* out) {
  const int gid = blockIdx.x * 256 + threadIdx.x;
  const int which = gid >> 20;
  const int loc = gid & 1048575;
  const float* src = which == 0 ? a : which == 1 ? b : c;
  float4 f = ((const float4*)src)[loc];
  ushort4 u = make_ushort4(f2bf(f.x), f2bf(f.y), f2bf(f.z), f2bf(f.w));
  *(ushort4*)(out + (size_t)which * 4194304 + (size_t)loc * 4) = u;
}

// ---------------- kernel 3: weight transpose + cvt (R3-proven) ----------------
__global__ __launch_bounds__(256) void k_wt(const float* w0, const float* w1,
                                            const float* w2, const float* w3,
                                            unsigned short* out) {
  __shared__ float t[32][33];
  const int z = blockIdx.z;
  const float* W = z == 0 ? w0 : z == 1 ? w1 : z == 2 ? w2 : w3;
  unsigned short* Wt = out + (size_t)z * 1048576;
  const int x = threadIdx.x, y = threadIdx.y;
  const int k0 = blockIdx.x * 32, n0 = blockIdx.y * 32;
#pragma unroll
  for (int r = 0; r < 4; ++r)
    t[y + r * 8][x] = W[(size_t)(k0 + y + r * 8) * 1024 + n0 + x];
  __syncthreads();
#pragma unroll
  for (int r = 0; r < 4; ++r)
    Wt[(size_t)(n0 + y + r * 8) * 1024 + k0 + x] = f2bf(t[x][y + r * 8]);
}

// ---------------- kernel 4: bf16 GEMM (R3-proven) ----------------
__global__ __launch_bounds__(256) void k_gemm(
    const unsigned short* __restrict__ A0, const unsigned short* __restrict__ A1,
    const unsigned short* __restrict__ A2, const unsigned short* __restrict__ B0,
    const unsigned short* __restrict__ B1, const unsigned short* __restrict__ B2,
    unsigned short* __restrict__ C0, unsigned short* __restrict__ C1,
    unsigned short* __restrict__ C2, float* __restrict__ Cf) {
  __shared__ __align__(16) unsigned short As[128 * 64];
  __shared__ __align__(16) unsigned short Bs[128 * 64];
  const int z = blockIdx.z;
  const unsigned short* A = z == 0 ? A0 : z == 1 ? A1 : A2;
  const unsigned short* Bt = z == 0 ? B0 : z == 1 ? B1 : B2;
  unsigned short* Cb = z == 0 ? C0 : z == 1 ? C1 : C2;

  const int tid = threadIdx.x, lane = tid & 63, wid = tid >> 6;
  const int mt = blockIdx.x, nt = blockIdx.y;
  const int wm = (wid >> 1) * 64, wn = (wid & 1) * 64;
  const int lr = lane >> 3;
  const int lc = ((lane & 7) ^ (lane >> 3)) * 8;
  const int l15 = lane & 15, lg = lane >> 4;
  f32x4 acc[4][4] = {};

  for (int kt = 0; kt < 16; ++kt) {
    const int k0 = kt * 64;
#pragma unroll
    for (int c = wid; c < 16; c += 4) {
      GLOAD16(A + (size_t)(mt * 128 + c * 8 + lr) * 1024 + k0 + lc, As + c * 512);
      GLOAD16(Bt + (size_t)(nt * 128 + c * 8 + lr) * 1024 + k0 + lc, Bs + c * 512);
    }
    __syncthreads();
#pragma unroll
    for (int ks = 0; ks < 2; ++ks) {
      const int ko = ks * 32 + lg * 8;
      bf16x8 af[4], bfr[4];
#pragma unroll
      for (int f = 0; f < 4; ++f) {
        af[f] = *(const bf16x8*)(As + swz(wm + f * 16 + l15, ko));
        bfr[f] = *(const bf16x8*)(Bs + swz(wn + f * 16 + l15, ko));
      }
#pragma unroll
      for (int i = 0; i < 4; ++i)
#pragma unroll
        for (int j = 0; j < 4; ++j)
          acc[i][j] = __builtin_amdgcn_mfma_f32_16x16x32_bf16(af[i], bfr[j],
                                                              acc[i][j], 0, 0, 0);
    }
    __syncthreads();
  }
  const int rbase = mt * 128 + wm + lg * 4;
  const int cbase = nt * 128 + wn + l15;
#pragma unroll
  for (int i = 0; i < 4; ++i)
#pragma unroll
    for (int j = 0; j < 4; ++j) {
      const int col = cbase + j * 16;
#pragma unroll
      for (int r = 0; r < 4; ++r) {
        const int row = rbase + i * 16 + r;
        if (Cf) Cf[(size_t)row * 1024 + col] = acc[i][j][r];
        else    Cb[(size_t)row * 1024 + col] = f2bf(acc[i][j][r]);
      }
    }
}

// ---------------- kernel 5a: flash attention -> CTX + reciprocal denoms ------
// R13-proven body + T5 setprio (R17-verified) around the per-kt compute.
__global__ __launch_bounds__(256) void k_attnA(
    const unsigned short* __restrict__ PQ, const unsigned short* __restrict__ PK,
    const unsigned short* __restrict__ PV_, const unsigned long long* __restrict__ bits,
    float* __restrict__ RS, unsigned short* __restrict__ CTX) {
  __shared__ __align__(16) unsigned short KB[2][64 * 64];
  __shared__ __align__(16) unsigned short VB[2][64 * 64];
  __shared__ __align__(16) unsigned short Ps[4][16 * 64];

  const int tid = threadIdx.x, lane = tid & 63, wid = tid >> 6;
  const int qt = blockIdx.x, h = blockIdx.y, b = blockIdx.z;
  const int q0 = qt * 64;
  const int lr = lane >> 3;
  const int lc = ((lane & 7) ^ (lane >> 3)) * 8;
  const int l15 = lane & 15, lg = lane >> 4;
  const size_t rowK = (size_t)(b * 2048) * 1024 + h * 64;
  const float C = 0.125f * 1.44269504f;

  // --- stage Q, read fragments ---
#pragma unroll
  for (int c = wid; c < 8; c += 4)
    GLOAD16(PQ + rowK + (size_t)(q0 + c * 8 + lr) * 1024 + lc, KB[0] + c * 512);
  __syncthreads();
  const bf16x8 qf0 = *(const bf16x8*)(KB[0] + swz(wid * 16 + l15, lg * 8));
  const bf16x8 qf1 = *(const bf16x8*)(KB[0] + swz(wid * 16 + l15, 32 + lg * 8));
  const unsigned long long* mrow =
      bits + (size_t)(b * 2048 + q0 + wid * 16 + lg * 4) * 32;
  __syncthreads();

  // --- stage K[0], V[0] ---
  const int vr = tid >> 3, d0 = (tid & 7) * 8;
  {
#pragma unroll
    for (int c = wid; c < 8; c += 4)
      GLOAD16(PK + rowK + (size_t)(c * 8 + lr) * 1024 + lc, KB[0] + c * 512);
    u16x8 v0 = *(const u16x8*)(PV_ + rowK + (size_t)vr * 1024 + d0);
    u16x8 v1 = *(const u16x8*)(PV_ + rowK + (size_t)(32 + vr) * 1024 + d0);
#pragma unroll
    for (int e = 0; e < 8; ++e) VB[0][swzV(d0 + e, vr)] = v0[e];
#pragma unroll
    for (int e = 0; e < 8; ++e) VB[0][swzV(d0 + e, 32 + vr)] = v1[e];
    __syncthreads();
  }

  float rs[4] = {0.f, 0.f, 0.f, 0.f};
  f32x4 cacc[4] = {};
  int cur = 0;
  for (int kt = 0; kt < 32; ++kt) {
    u16x8 nv0, nv1;
    if (kt < 31) {
      const size_t nb = rowK + (size_t)((kt + 1) * 64) * 1024;
      nv0 = *(const u16x8*)(PV_ + nb + (size_t)vr * 1024 + d0);
      nv1 = *(const u16x8*)(PV_ + nb + (size_t)(32 + vr) * 1024 + d0);
#pragma unroll
      for (int c = wid; c < 8; c += 4)
        GLOAD16(PK + nb + (size_t)(c * 8 + lr) * 1024 + lc, KB[cur ^ 1] + c * 512);
    }
    const unsigned long long wm_[4] = {mrow[kt], mrow[32 + kt], mrow[64 + kt],
                                       mrow[96 + kt]};
    __builtin_amdgcn_s_setprio(1);
#pragma unroll
    for (int fn = 0; fn < 4; ++fn) {
      const bf16x8 kf0 = *(const bf16x8*)(KB[cur] + swz(fn * 16 + l15, lg * 8));
      const bf16x8 kf1 = *(const bf16x8*)(KB[cur] + swz(fn * 16 + l15, 32 + lg * 8));
      f32x4 s = {};
      s = __builtin_amdgcn_mfma_f32_16x16x32_bf16(qf0, kf0, s, 0, 0, 0);
      s = __builtin_amdgcn_mfma_f32_16x16x32_bf16(qf1, kf1, s, 0, 0, 0);
      const int kb = fn * 16 + l15;
#pragma unroll
      for (int r = 0; r < 4; ++r) {
        const float p =
            ((wm_[r] >> kb) & 1) ? 0.f : fast_exp2(s[r] * C);
        rs[r] += p;
        Ps[wid][swz(lg * 4 + r, kb)] = f2bf_hw(p);
      }
    }
    // PV accumulate (unnormalized)
#pragma unroll
    for (int ks = 0; ks < 2; ++ks) {
      const int ko = ks * 32 + lg * 8;
      const bf16x8 pf = *(const bf16x8*)(&Ps[wid][swz(l15, ko)]);
#pragma unroll
      for (int fn = 0; fn < 4; ++fn) {
        const bf16x8 vf = *(const bf16x8*)(VB[cur] + swzV(fn * 16 + l15, ko));
        cacc[fn] = __builtin_amdgcn_mfma_f32_16x16x32_bf16(pf, vf, cacc[fn], 0, 0, 0);
      }
    }
    __builtin_amdgcn_s_setprio(0);
    if (kt < 31) {
#pragma unroll
      for (int e = 0; e < 8; ++e) VB[cur ^ 1][swzV(d0 + e, vr)] = nv0[e];
#pragma unroll
      for (int e = 0; e < 8; ++e) VB[cur ^ 1][swzV(d0 + e, 32 + vr)] = nv1[e];
    }
    __syncthreads();
    cur ^= 1;
  }
  float rsr[4];
#pragma unroll
  for (int r = 0; r < 4; ++r) {
#pragma unroll
    for (int m = 1; m < 16; m <<= 1) rs[r] += __shfl_xor(rs[r], m);
    rsr[r] = 1.f / rs[r];
  }
#pragma unroll
  for (int fn = 0; fn < 4; ++fn)
#pragma unroll
    for (int r = 0; r < 4; ++r) {
      const int q = q0 + wid * 16 + lg * 4 + r;
      CTX[(size_t)(b * 2048 + q) * 1024 + h * 64 + fn * 16 + l15] =
          f2bf_hw(cacc[fn][r] * rsr[r]);
    }
  if (l15 == 0) {
#pragma unroll
    for (int r = 0; r < 4; ++r)
      RS[(size_t)(b * 16 + h) * 2048 + q0 + wid * 16 + lg * 4 + r] = rsr[r];
  }
}

// ---------------- kernel 5c: attn-matrix store, 4-way k-split ----------------
// R13-proven body + T5 setprio (R17) + NON-TEMPORAL output stores (f32x4
// ext_vector form — __builtin_nontemporal_store rejects HIP float4 struct).
__global__ __launch_bounds__(256) void k_attnC(
    const unsigned short* __restrict__ PQ, const unsigned short* __restrict__ PK,
    const unsigned long long* __restrict__ bits, const float* __restrict__ RS,
    float* __restrict__ attn_out) {
  __shared__ __align__(16) unsigned short KB[2][64 * 64];
  __shared__ __align__(16) unsigned short Ps[4][16 * 64];

  const int tid = threadIdx.x, lane = tid & 63, wid = tid >> 6;
  const int qt = blockIdx.x, h = blockIdx.y;
  const int b = blockIdx.z >> 2, kq = blockIdx.z & 3;
  const int ktlo = kq * 8, kthi = ktlo + 8;
  const int q0 = qt * 64;
  const int lr = lane >> 3;
  const int lc = ((lane & 7) ^ (lane >> 3)) * 8;
  const int l15 = lane & 15, lg = lane >> 4;
  const size_t rowK = (size_t)(b * 2048) * 1024 + h * 64;
  const float C = 0.125f * 1.44269504f;

#pragma unroll
  for (int c = wid; c < 8; c += 4)
    GLOAD16(PQ + rowK + (size_t)(q0 + c * 8 + lr) * 1024 + lc, KB[0] + c * 512);
  __syncthreads();
  const bf16x8 qf0 = *(const bf16x8*)(KB[0] + swz(wid * 16 + l15, lg * 8));
  const bf16x8 qf1 = *(const bf16x8*)(KB[0] + swz(wid * 16 + l15, 32 + lg * 8));
  const unsigned long long* mrow =
      bits + (size_t)(b * 2048 + q0 + wid * 16 + lg * 4) * 32;
  float rsr[4];
#pragma unroll
  for (int r = 0; r < 4; ++r)
    rsr[r] = RS[(size_t)(b * 16 + h) * 2048 + q0 + wid * 16 + lg * 4 + r];
  __syncthreads();

#pragma unroll
  for (int c = wid; c < 8; c += 4)
    GLOAD16(PK + rowK + (size_t)(ktlo * 64 + c * 8 + lr) * 1024 + lc,
            KB[0] + c * 512);
  __syncthreads();

  const int srow = lane >> 2, scg = lane & 3;
  float* arow = attn_out + ((size_t)(b * 16 + h) * 2048 + q0 + wid * 16 + srow) * 2048;
  int cur = 0;
  for (int kt = ktlo; kt < kthi; ++kt) {
    const int k0 = kt * 64;
    if (kt < kthi - 1) {
#pragma unroll
      for (int c = wid; c < 8; c += 4)
        GLOAD16(PK + rowK + (size_t)((kt + 1) * 64 + c * 8 + lr) * 1024 + lc,
                KB[cur ^ 1] + c * 512);
    }
    const unsigned long long wm_[4] = {mrow[kt], mrow[32 + kt], mrow[64 + kt],
                                       mrow[96 + kt]};
    __builtin_amdgcn_s_setprio(1);
#pragma unroll
    for (int fn = 0; fn < 4; ++fn) {
      const bf16x8 kf0 = *(const bf16x8*)(KB[cur] + swz(fn * 16 + l15, lg * 8));
      const bf16x8 kf1 = *(const bf16x8*)(KB[cur] + swz(fn * 16 + l15, 32 + lg * 8));
      f32x4 s = {};
      s = __builtin_amdgcn_mfma_f32_16x16x32_bf16(qf0, kf0, s, 0, 0, 0);
      s = __builtin_amdgcn_mfma_f32_16x16x32_bf16(qf1, kf1, s, 0, 0, 0);
      const int kb = fn * 16 + l15;
#pragma unroll
      for (int r = 0; r < 4; ++r) {
        const float p =
            ((wm_[r] >> kb) & 1) ? 0.f : fast_exp2(s[r] * C) * rsr[r];
        Ps[wid][swz(lg * 4 + r, kb)] = f2bf_hw(p);
      }
    }
    __builtin_amdgcn_s_setprio(0);
#pragma unroll
    for (int j = 0; j < 4; ++j) {
      const int c = scg * 4 + j * 16;
      const u16x4 pb = *(const u16x4*)(&Ps[wid][swz(srow, c)]);
      f32x4 o;
      o[0] = bf2f(pb[0]); o[1] = bf2f(pb[1]);
      o[2] = bf2f(pb[2]); o[3] = bf2f(pb[3]);
      __builtin_nontemporal_store(o, (f32x4*)(arow + k0 + c));
    }
    __syncthreads();
    cur ^= 1;
  }
}

// ---------------- kernel 6: residual + LayerNorm (R3-proven) ----------------
__global__ __launch_bounds__(256) void k_ln(const float* __restrict__ PRE,
                                            const float* __restrict__ inQ,
                                            float* __restrict__ out) {
  const int row = blockIdx.x, tid = threadIdx.x;
  const size_t base = (size_t)row * 1024 + tid * 4;
  const float4 x = *(const float4*)(PRE + base);
  const float4 q = *(const float4*)(inQ + base);
  const float v0 = x.x + q.x, v1 = x.y + q.y, v2 = x.z + q.z, v3 = x.w + q.w;
  float s = v0 + v1 + v2 + v3;
  float ss = v0 * v0 + v1 * v1 + v2 * v2 + v3 * v3;
#pragma unroll
  for (int m = 1; m < 64; m <<= 1) {
    s += __shfl_xor(s, m);
    ss += __shfl_xor(ss, m);
  }
  __shared__ float red[8];
  const int wid = tid >> 6, lane = tid & 63;
  if (lane == 0) { red[wid] = s; red[4 + wid] = ss; }
  __syncthreads();
  if (tid == 0) {
    const float S = red[0] + red[1] + red[2] + red[3];
    const float SS = red[4] + red[5] + red[6] + red[7];
    const float mu = S * (1.f / 1024.f);
    const float var = SS * (1.f / 1024.f) - mu * mu;
    red[0] = mu;
    red[1] = rsqrtf(var + 1e-5f);
  }
  __syncthreads();
  const float mu = red[0], rstd = red[1];
  float4 o;
  o.x = (v0 - mu) * rstd; o.y = (v1 - mu) * rstd;
  o.z = (v2 - mu) * rstd; o.w = (v3 - mu) * rstd;
  *(float4*)(out + base) = o;
}

extern "C" void kernel_launch(void* const* d_in, const int* in_sizes, int n_in,
                              void* d_out, int out_size, void* d_ws, size_t ws_size,
                              hipStream_t stream) {
  const float* inQ = (const float*)d_in[0];
  const float* inK = (const float*)d_in[1];
  const float* inV = (const float*)d_in[2];
  const void* msk = d_in[3];
  const float* wq = (const float*)d_in[4];
  const float* wk = (const float*)d_in[5];
  const float* wv = (const float*)d_in[6];
  const float* wf = (const float*)d_in[7];

  char* ws = (char*)d_ws;
  unsigned short* XQ = (unsigned short*)(ws);
  unsigned short* WT = (unsigned short*)(ws + 25165824);
  unsigned short* PQ = (unsigned short*)(ws + 33554432);
  unsigned short* PK = (unsigned short*)(ws + 41943040);
  unsigned short* PV = (unsigned short*)(ws + 50331648);
  unsigned short* CTX = (unsigned short*)(ws + 58720256);
  float* PRE = (float*)(ws + 67108864);
  unsigned long long* BITS = (unsigned long long*)(ws + 83886080);
  float* RS = (float*)(ws + 84934656);
  int* FLAG = (int*)(ws + 85196800);

  float* outLN = (float*)d_out;
  float* outAT = (float*)d_out + 4194304;

  k_detect<<<1, 256, 0, stream>>>((const unsigned*)msk, FLAG);
  k_pack<<<32768, 256, 0, stream>>>(msk, FLAG, BITS);
  k_cvt<<<12288, 256, 0, stream>>>(inQ, inK, inV, XQ);
  k_wt<<<dim3(32, 32, 4), dim3(32, 8, 1), 0, stream>>>(wq, wk, wv, wf, WT);
  k_gemm<<<dim3(32, 8, 3), 256, 0, stream>>>(XQ, XQ + 4194304, XQ + 8388608,
                                             WT, WT + 1048576, WT + 2097152,
                                             PQ, PK, PV, nullptr);
  k_attnA<<<dim3(32, 16, 2), 256, 0, stream>>>(PQ, PK, PV, BITS, RS, CTX);
  k_attnC<<<dim3(32, 16, 8), 256, 0, stream>>>(PQ, PK, BITS, RS, outAT);
  k_gemm<<<dim3(32, 8, 1), 256, 0, stream>>>(CTX, CTX, CTX, WT + 3145728,
                                             WT + 3145728, WT + 3145728,
                                             nullptr, nullptr, nullptr, PRE);
  k_ln<<<4096, 256, 0, stream>>>(PRE, inQ, outLN);
}

// Round 20
// 357.853 us; speedup vs baseline: 1.0730x; 1.0730x over previous
//
#include <hip/hip_runtime.h>

typedef __bf16 bf16x8 __attribute__((ext_vector_type(8)));
typedef unsigned short u16x8 __attribute__((ext_vector_type(8)));
typedef unsigned short u16x4 __attribute__((ext_vector_type(4)));
typedef float f32x4 __attribute__((ext_vector_type(4)));

#define DEV static __device__ __forceinline__

DEV unsigned short f2bf(float f) {
  union { float f; unsigned u; } v; v.f = f;
  unsigned u = v.u + 0x7FFFu + ((v.u >> 16) & 1u);
  return (unsigned short)(u >> 16);
}

// HW bf16 convert (v_cvt, RNE) - 1 VALU op vs 4 for the manual version.
DEV unsigned short f2bf_hw(float f) {
  union { __bf16 b; unsigned short u; } v;
  v.b = (__bf16)f;
  return v.u;
}

DEV float bf2f(unsigned short b) {
  union { unsigned u; float f; } v; v.u = ((unsigned)b) << 16;
  return v.f;
}

DEV float fast_exp2(float x) { return __builtin_amdgcn_exp2f(x); }

// XOR swizzle within a [row][64] bf16 tile: element offset.
DEV int swz(int row, int k) { return row * 64 + (k ^ ((row & 7) * 8)); }

// V-tile swizzle: extra (row>>3) XOR term for the register-staged V transpose
// (verified: SQ_LDS_BANK_CONFLICT 5.87e7 -> 8.4e6, R10->R12).
DEV int swzV(int row, int k) {
  return row * 64 + (k ^ ((row & 7) * 8) ^ (((row >> 3) & 7) * 8));
}

#define GLOAD16(gp, lp)                                                        \
  __builtin_amdgcn_global_load_lds(                                            \
      (const __attribute__((address_space(1))) void*)(const void*)(gp),        \
      (__attribute__((address_space(3))) void*)(void*)(lp), 16, 0, 0)

// ---------------- kernel 0: detect mask dtype (R3-proven) ----------------
__global__ __launch_bounds__(256) void k_detect(const unsigned* m, int* flag) {
  __shared__ int sF, sI;
  if (threadIdx.x == 0) { sF = 1; sI = 1; }
  __syncthreads();
  int lF = 1, lI = 1;
  for (int i = threadIdx.x; i < 4096; i += 256) {
    unsigned d = m[i];
    lF &= (d == 0u || d == 0x3F800000u);
    lI &= (d == 0u || d == 1u);
  }
  if (!lF) atomicAnd(&sF, 0);
  if (!lI) atomicAnd(&sI, 0);
  __syncthreads();
  if (threadIdx.x == 0) flag[0] = sF ? 2 : (sI ? 0 : 1);
}

// ---------------- kernel 1: pack mask to bitmask (R3-proven) ----------------
__global__ __launch_bounds__(256) void k_pack(const void* m, const int* flag,
                                              unsigned long long* bits) {
  const int tid = threadIdx.x;
  const int w = blockIdx.x * 4 + (tid >> 6);
  const int lane = tid & 63;
  const size_t idx = (size_t)w * 64 + lane;
  const int fl = flag[0];
  int v;
  if (fl == 1)      v = ((const unsigned char*)m)[idx];
  else if (fl == 0) v = ((const int*)m)[idx];
  else              v = (((const float*)m)[idx] != 0.f);
  unsigned long long bal = __ballot(v != 0);
  if (lane == 0) bits[w] = bal;
}

// ---------------- kernel 2: fp32 -> bf16 (R3-proven) ----------------
__global__ __launch_bounds__(256) void k_cvt(const float* a, const float* b,
                                             const float* c, unsigned short* out) {
  const int gid = blockIdx.x * 256 + threadIdx.x;
  const int which = gid >> 20;
  const int loc = gid & 1048575;
  const float* src = which == 0 ? a : which == 1 ? b : c;
  float4 f = ((const float4*)src)[loc];
  ushort4 u = make_ushort4(f2bf(f.x), f2bf(f.y), f2bf(f.z), f2bf(f.w));
  *(ushort4*)(out + (size_t)which * 4194304 + (size_t)loc * 4) = u;
}

// ---------------- kernel 3: weight transpose + cvt (R3-proven) ----------------
__global__ __launch_bounds__(256) void k_wt(const float* w0, const float* w1,
                                            const float* w2, const float* w3,
                                            unsigned short* out) {
  __shared__ float t[32][33];
  const int z = blockIdx.z;
  const float* W = z == 0 ? w0 : z == 1 ? w1 : z == 2 ? w2 : w3;
  unsigned short* Wt = out + (size_t)z * 1048576;
  const int x = threadIdx.x, y = threadIdx.y;
  const int k0 = blockIdx.x * 32, n0 = blockIdx.y * 32;
#pragma unroll
  for (int r = 0; r < 4; ++r)
    t[y + r * 8][x] = W[(size_t)(k0 + y + r * 8) * 1024 + n0 + x];
  __syncthreads();
#pragma unroll
  for (int r = 0; r < 4; ++r)
    Wt[(size_t)(n0 + y + r * 8) * 1024 + k0 + x] = f2bf(t[x][y + r * 8]);
}

// ---------------- kernel 4: bf16 GEMM (R3-proven) ----------------
__global__ __launch_bounds__(256) void k_gemm(
    const unsigned short* __restrict__ A0, const unsigned short* __restrict__ A1,
    const unsigned short* __restrict__ A2, const unsigned short* __restrict__ B0,
    const unsigned short* __restrict__ B1, const unsigned short* __restrict__ B2,
    unsigned short* __restrict__ C0, unsigned short* __restrict__ C1,
    unsigned short* __restrict__ C2, float* __restrict__ Cf) {
  __shared__ __align__(16) unsigned short As[128 * 64];
  __shared__ __align__(16) unsigned short Bs[128 * 64];
  const int z = blockIdx.z;
  const unsigned short* A = z == 0 ? A0 : z == 1 ? A1 : A2;
  const unsigned short* Bt = z == 0 ? B0 : z == 1 ? B1 : B2;
  unsigned short* Cb = z == 0 ? C0 : z == 1 ? C1 : C2;

  const int tid = threadIdx.x, lane = tid & 63, wid = tid >> 6;
  const int mt = blockIdx.x, nt = blockIdx.y;
  const int wm = (wid >> 1) * 64, wn = (wid & 1) * 64;
  const int lr = lane >> 3;
  const int lc = ((lane & 7) ^ (lane >> 3)) * 8;
  const int l15 = lane & 15, lg = lane >> 4;
  f32x4 acc[4][4] = {};

  for (int kt = 0; kt < 16; ++kt) {
    const int k0 = kt * 64;
#pragma unroll
    for (int c = wid; c < 16; c += 4) {
      GLOAD16(A + (size_t)(mt * 128 + c * 8 + lr) * 1024 + k0 + lc, As + c * 512);
      GLOAD16(Bt + (size_t)(nt * 128 + c * 8 + lr) * 1024 + k0 + lc, Bs + c * 512);
    }
    __syncthreads();
#pragma unroll
    for (int ks = 0; ks < 2; ++ks) {
      const int ko = ks * 32 + lg * 8;
      bf16x8 af[4], bfr[4];
#pragma unroll
      for (int f = 0; f < 4; ++f) {
        af[f] = *(const bf16x8*)(As + swz(wm + f * 16 + l15, ko));
        bfr[f] = *(const bf16x8*)(Bs + swz(wn + f * 16 + l15, ko));
      }
#pragma unroll
      for (int i = 0; i < 4; ++i)
#pragma unroll
        for (int j = 0; j < 4; ++j)
          acc[i][j] = __builtin_amdgcn_mfma_f32_16x16x32_bf16(af[i], bfr[j],
                                                              acc[i][j], 0, 0, 0);
    }
    __syncthreads();
  }
  const int rbase = mt * 128 + wm + lg * 4;
  const int cbase = nt * 128 + wn + l15;
#pragma unroll
  for (int i = 0; i < 4; ++i)
#pragma unroll
    for (int j = 0; j < 4; ++j) {
      const int col = cbase + j * 16;
#pragma unroll
      for (int r = 0; r < 4; ++r) {
        const int row = rbase + i * 16 + r;
        if (Cf) Cf[(size_t)row * 1024 + col] = acc[i][j][r];
        else    Cb[(size_t)row * 1024 + col] = f2bf(acc[i][j][r]);
      }
    }
}

// ---------------- kernel 5a: flash attention -> CTX + reciprocal denoms ------
// R13-proven body + T5 setprio (R17-verified) around the per-kt compute.
__global__ __launch_bounds__(256) void k_attnA(
    const unsigned short* __restrict__ PQ, const unsigned short* __restrict__ PK,
    const unsigned short* __restrict__ PV_, const unsigned long long* __restrict__ bits,
    float* __restrict__ RS, unsigned short* __restrict__ CTX) {
  __shared__ __align__(16) unsigned short KB[2][64 * 64];
  __shared__ __align__(16) unsigned short VB[2][64 * 64];
  __shared__ __align__(16) unsigned short Ps[4][16 * 64];

  const int tid = threadIdx.x, lane = tid & 63, wid = tid >> 6;
  const int qt = blockIdx.x, h = blockIdx.y, b = blockIdx.z;
  const int q0 = qt * 64;
  const int lr = lane >> 3;
  const int lc = ((lane & 7) ^ (lane >> 3)) * 8;
  const int l15 = lane & 15, lg = lane >> 4;
  const size_t rowK = (size_t)(b * 2048) * 1024 + h * 64;
  const float C = 0.125f * 1.44269504f;

  // --- stage Q, read fragments ---
#pragma unroll
  for (int c = wid; c < 8; c += 4)
    GLOAD16(PQ + rowK + (size_t)(q0 + c * 8 + lr) * 1024 + lc, KB[0] + c * 512);
  __syncthreads();
  const bf16x8 qf0 = *(const bf16x8*)(KB[0] + swz(wid * 16 + l15, lg * 8));
  const bf16x8 qf1 = *(const bf16x8*)(KB[0] + swz(wid * 16 + l15, 32 + lg * 8));
  const unsigned long long* mrow =
      bits + (size_t)(b * 2048 + q0 + wid * 16 + lg * 4) * 32;
  __syncthreads();

  // --- stage K[0], V[0] ---
  const int vr = tid >> 3, d0 = (tid & 7) * 8;
  {
#pragma unroll
    for (int c = wid; c < 8; c += 4)
      GLOAD16(PK + rowK + (size_t)(c * 8 + lr) * 1024 + lc, KB[0] + c * 512);
    u16x8 v0 = *(const u16x8*)(PV_ + rowK + (size_t)vr * 1024 + d0);
    u16x8 v1 = *(const u16x8*)(PV_ + rowK + (size_t)(32 + vr) * 1024 + d0);
#pragma unroll
    for (int e = 0; e < 8; ++e) VB[0][swzV(d0 + e, vr)] = v0[e];
#pragma unroll
    for (int e = 0; e < 8; ++e) VB[0][swzV(d0 + e, 32 + vr)] = v1[e];
    __syncthreads();
  }

  float rs[4] = {0.f, 0.f, 0.f, 0.f};
  f32x4 cacc[4] = {};
  int cur = 0;
  for (int kt = 0; kt < 32; ++kt) {
    u16x8 nv0, nv1;
    if (kt < 31) {
      const size_t nb = rowK + (size_t)((kt + 1) * 64) * 1024;
      nv0 = *(const u16x8*)(PV_ + nb + (size_t)vr * 1024 + d0);
      nv1 = *(const u16x8*)(PV_ + nb + (size_t)(32 + vr) * 1024 + d0);
#pragma unroll
      for (int c = wid; c < 8; c += 4)
        GLOAD16(PK + nb + (size_t)(c * 8 + lr) * 1024 + lc, KB[cur ^ 1] + c * 512);
    }
    const unsigned long long wm_[4] = {mrow[kt], mrow[32 + kt], mrow[64 + kt],
                                       mrow[96 + kt]};
    __builtin_amdgcn_s_setprio(1);
#pragma unroll
    for (int fn = 0; fn < 4; ++fn) {
      const bf16x8 kf0 = *(const bf16x8*)(KB[cur] + swz(fn * 16 + l15, lg * 8));
      const bf16x8 kf1 = *(const bf16x8*)(KB[cur] + swz(fn * 16 + l15, 32 + lg * 8));
      f32x4 s = {};
      s = __builtin_amdgcn_mfma_f32_16x16x32_bf16(qf0, kf0, s, 0, 0, 0);
      s = __builtin_amdgcn_mfma_f32_16x16x32_bf16(qf1, kf1, s, 0, 0, 0);
      const int kb = fn * 16 + l15;
#pragma unroll
      for (int r = 0; r < 4; ++r) {
        const float p =
            ((wm_[r] >> kb) & 1) ? 0.f : fast_exp2(s[r] * C);
        rs[r] += p;
        Ps[wid][swz(lg * 4 + r, kb)] = f2bf_hw(p);
      }
    }
    // PV accumulate (unnormalized)
#pragma unroll
    for (int ks = 0; ks < 2; ++ks) {
      const int ko = ks * 32 + lg * 8;
      const bf16x8 pf = *(const bf16x8*)(&Ps[wid][swz(l15, ko)]);
#pragma unroll
      for (int fn = 0; fn < 4; ++fn) {
        const bf16x8 vf = *(const bf16x8*)(VB[cur] + swzV(fn * 16 + l15, ko));
        cacc[fn] = __builtin_amdgcn_mfma_f32_16x16x32_bf16(pf, vf, cacc[fn], 0, 0, 0);
      }
    }
    __builtin_amdgcn_s_setprio(0);
    if (kt < 31) {
#pragma unroll
      for (int e = 0; e < 8; ++e) VB[cur ^ 1][swzV(d0 + e, vr)] = nv0[e];
#pragma unroll
      for (int e = 0; e < 8; ++e) VB[cur ^ 1][swzV(d0 + e, 32 + vr)] = nv1[e];
    }
    __syncthreads();
    cur ^= 1;
  }
  float rsr[4];
#pragma unroll
  for (int r = 0; r < 4; ++r) {
#pragma unroll
    for (int m = 1; m < 16; m <<= 1) rs[r] += __shfl_xor(rs[r], m);
    rsr[r] = 1.f / rs[r];
  }
#pragma unroll
  for (int fn = 0; fn < 4; ++fn)
#pragma unroll
    for (int r = 0; r < 4; ++r) {
      const int q = q0 + wid * 16 + lg * 4 + r;
      CTX[(size_t)(b * 2048 + q) * 1024 + h * 64 + fn * 16 + l15] =
          f2bf_hw(cacc[fn][r] * rsr[r]);
    }
  if (l15 == 0) {
#pragma unroll
    for (int r = 0; r < 4; ++r)
      RS[(size_t)(b * 16 + h) * 2048 + q0 + wid * 16 + lg * 4 + r] = rsr[r];
  }
}

// ---------------- kernel 5c: attn-matrix store, 4-way k-split ----------------
// R13-proven body + T5 setprio (R17-verified). Plain float4 stores (nt
// regressed -25us in R19 -> L2 write-aggregation helps this store pattern).
__global__ __launch_bounds__(256) void k_attnC(
    const unsigned short* __restrict__ PQ, const unsigned short* __restrict__ PK,
    const unsigned long long* __restrict__ bits, const float* __restrict__ RS,
    float* __restrict__ attn_out) {
  __shared__ __align__(16) unsigned short KB[2][64 * 64];
  __shared__ __align__(16) unsigned short Ps[4][16 * 64];

  const int tid = threadIdx.x, lane = tid & 63, wid = tid >> 6;
  const int qt = blockIdx.x, h = blockIdx.y;
  const int b = blockIdx.z >> 2, kq = blockIdx.z & 3;
  const int ktlo = kq * 8, kthi = ktlo + 8;
  const int q0 = qt * 64;
  const int lr = lane >> 3;
  const int lc = ((lane & 7) ^ (lane >> 3)) * 8;
  const int l15 = lane & 15, lg = lane >> 4;
  const size_t rowK = (size_t)(b * 2048) * 1024 + h * 64;
  const float C = 0.125f * 1.44269504f;

#pragma unroll
  for (int c = wid; c < 8; c += 4)
    GLOAD16(PQ + rowK + (size_t)(q0 + c * 8 + lr) * 1024 + lc, KB[0] + c * 512);
  __syncthreads();
  const bf16x8 qf0 = *(const bf16x8*)(KB[0] + swz(wid * 16 + l15, lg * 8));
  const bf16x8 qf1 = *(const bf16x8*)(KB[0] + swz(wid * 16 + l15, 32 + lg * 8));
  const unsigned long long* mrow =
      bits + (size_t)(b * 2048 + q0 + wid * 16 + lg * 4) * 32;
  float rsr[4];
#pragma unroll
  for (int r = 0; r < 4; ++r)
    rsr[r] = RS[(size_t)(b * 16 + h) * 2048 + q0 + wid * 16 + lg * 4 + r];
  __syncthreads();

#pragma unroll
  for (int c = wid; c < 8; c += 4)
    GLOAD16(PK + rowK + (size_t)(ktlo * 64 + c * 8 + lr) * 1024 + lc,
            KB[0] + c * 512);
  __syncthreads();

  const int srow = lane >> 2, scg = lane & 3;
  float* arow = attn_out + ((size_t)(b * 16 + h) * 2048 + q0 + wid * 16 + srow) * 2048;
  int cur = 0;
  for (int kt = ktlo; kt < kthi; ++kt) {
    const int k0 = kt * 64;
    if (kt < kthi - 1) {
#pragma unroll
      for (int c = wid; c < 8; c += 4)
        GLOAD16(PK + rowK + (size_t)((kt + 1) * 64 + c * 8 + lr) * 1024 + lc,
                KB[cur ^ 1] + c * 512);
    }
    const unsigned long long wm_[4] = {mrow[kt], mrow[32 + kt], mrow[64 + kt],
                                       mrow[96 + kt]};
    __builtin_amdgcn_s_setprio(1);
#pragma unroll
    for (int fn = 0; fn < 4; ++fn) {
      const bf16x8 kf0 = *(const bf16x8*)(KB[cur] + swz(fn * 16 + l15, lg * 8));
      const bf16x8 kf1 = *(const bf16x8*)(KB[cur] + swz(fn * 16 + l15, 32 + lg * 8));
      f32x4 s = {};
      s = __builtin_amdgcn_mfma_f32_16x16x32_bf16(qf0, kf0, s, 0, 0, 0);
      s = __builtin_amdgcn_mfma_f32_16x16x32_bf16(qf1, kf1, s, 0, 0, 0);
      const int kb = fn * 16 + l15;
#pragma unroll
      for (int r = 0; r < 4; ++r) {
        const float p =
            ((wm_[r] >> kb) & 1) ? 0.f : fast_exp2(s[r] * C) * rsr[r];
        Ps[wid][swz(lg * 4 + r, kb)] = f2bf_hw(p);
      }
    }
    __builtin_amdgcn_s_setprio(0);
#pragma unroll
    for (int j = 0; j < 4; ++j) {
      const int c = scg * 4 + j * 16;
      const u16x4 pb = *(const u16x4*)(&Ps[wid][swz(srow, c)]);
      float4 o;
      o.x = bf2f(pb[0]); o.y = bf2f(pb[1]); o.z = bf2f(pb[2]); o.w = bf2f(pb[3]);
      *(float4*)(arow + k0 + c) = o;
    }
    __syncthreads();
    cur ^= 1;
  }
}

// ---------------- kernel 6: residual + LayerNorm (R3-proven) ----------------
__global__ __launch_bounds__(256) void k_ln(const float* __restrict__ PRE,
                                            const float* __restrict__ inQ,
                                            float* __restrict__ out) {
  const int row = blockIdx.x, tid = threadIdx.x;
  const size_t base = (size_t)row * 1024 + tid * 4;
  const float4 x = *(const float4*)(PRE + base);
  const float4 q = *(const float4*)(inQ + base);
  const float v0 = x.x + q.x, v1 = x.y + q.y, v2 = x.z + q.z, v3 = x.w + q.w;
  float s = v0 + v1 + v2 + v3;
  float ss = v0 * v0 + v1 * v1 + v2 * v2 + v3 * v3;
#pragma unroll
  for (int m = 1; m < 64; m <<= 1) {
    s += __shfl_xor(s, m);
    ss += __shfl_xor(ss, m);
  }
  __shared__ float red[8];
  const int wid = tid >> 6, lane = tid & 63;
  if (lane == 0) { red[wid] = s; red[4 + wid] = ss; }
  __syncthreads();
  if (tid == 0) {
    const float S = red[0] + red[1] + red[2] + red[3];
    const float SS = red[4] + red[5] + red[6] + red[7];
    const float mu = S * (1.f / 1024.f);
    const float var = SS * (1.f / 1024.f) - mu * mu;
    red[0] = mu;
    red[1] = rsqrtf(var + 1e-5f);
  }
  __syncthreads();
  const float mu = red[0], rstd = red[1];
  float4 o;
  o.x = (v0 - mu) * rstd; o.y = (v1 - mu) * rstd;
  o.z = (v2 - mu) * rstd; o.w = (v3 - mu) * rstd;
  *(float4*)(out + base) = o;
}

extern "C" void kernel_launch(void* const* d_in, const int* in_sizes, int n_in,
                              void* d_out, int out_size, void* d_ws, size_t ws_size,
                              hipStream_t stream) {
  const float* inQ = (const float*)d_in[0];
  const float* inK = (const float*)d_in[1];
  const float* inV = (const float*)d_in[2];
  const void* msk = d_in[3];
  const float* wq = (const float*)d_in[4];
  const float* wk = (const float*)d_in[5];
  const float* wv = (const float*)d_in[6];
  const float* wf = (const float*)d_in[7];

  char* ws = (char*)d_ws;
  unsigned short* XQ = (unsigned short*)(ws);
  unsigned short* WT = (unsigned short*)(ws + 25165824);
  unsigned short* PQ = (unsigned short*)(ws + 33554432);
  unsigned short* PK = (unsigned short*)(ws + 41943040);
  unsigned short* PV = (unsigned short*)(ws + 50331648);
  unsigned short* CTX = (unsigned short*)(ws + 58720256);
  float* PRE = (float*)(ws + 67108864);
  unsigned long long* BITS = (unsigned long long*)(ws + 83886080);
  float* RS = (float*)(ws + 84934656);
  int* FLAG = (int*)(ws + 85196800);

  float* outLN = (float*)d_out;
  float* outAT = (float*)d_out + 4194304;

  k_detect<<<1, 256, 0, stream>>>((const unsigned*)msk, FLAG);
  k_pack<<<32768, 256, 0, stream>>>(msk, FLAG, BITS);
  k_cvt<<<12288, 256, 0, stream>>>(inQ, inK, inV, XQ);
  k_wt<<<dim3(32, 32, 4), dim3(32, 8, 1), 0, stream>>>(wq, wk, wv, wf, WT);
  k_gemm<<<dim3(32, 8, 3), 256, 0, stream>>>(XQ, XQ + 4194304, XQ + 8388608,
                                             WT, WT + 1048576, WT + 2097152,
                                             PQ, PK, PV, nullptr);
  k_attnA<<<dim3(32, 16, 2), 256, 0, stream>>>(PQ, PK, PV, BITS, RS, CTX);
  k_attnC<<<dim3(32, 16, 8), 256, 0, stream>>>(PQ, PK, BITS, RS, outAT);
  k_gemm<<<dim3(32, 8, 1), 256, 0, stream>>>(CTX, CTX, CTX, WT + 3145728,
                                             WT + 3145728, WT + 3145728,
                                             nullptr, nullptr, nullptr, PRE);
  k_ln<<<4096, 256, 0, stream>>>(PRE, inQ, outLN);
}